// Round 6
// baseline (319.602 us; speedup 1.0000x reference)
//
#include <hip/hip_runtime.h>

#define S_LEN 2048
#define D_MODEL 1024
#define NH 16
#define DHEAD 64
#define BATCH 4

typedef _Float16 half8 __attribute__((ext_vector_type(8)));
typedef __fp16 fp16x2 __attribute__((ext_vector_type(2)));
typedef float floatx4 __attribute__((ext_vector_type(4)));

#define EXP2SCALE 0.1803368801111244f   // (1/sqrt(64)) * log2(e), folded into Q projection

__device__ __forceinline__ unsigned short f2h(float f) {
    _Float16 h = (_Float16)f;
    return __builtin_bit_cast(unsigned short, h);
}

// pack two floats -> 2x fp16 (RTZ) as uint bits
__device__ __forceinline__ unsigned int pk2(float a, float b) {
    fp16x2 p = __builtin_amdgcn_cvt_pkrtz(a, b);
    return __builtin_bit_cast(unsigned int, p);
}

// async global->LDS, 16B per lane; lds dest = wave-uniform base + lane*16
__device__ __forceinline__ void gload_lds16(const unsigned short* g, unsigned short* l) {
    __builtin_amdgcn_global_load_lds(
        (const __attribute__((address_space(1))) void*)g,
        (__attribute__((address_space(3))) void*)l,
        16, 0, 0);
}

// ---------------- conversion: fp32 -> fp16 bits ---------------------------------
__global__ __launch_bounds__(256) void convert_f2h_kernel(const float* __restrict__ in,
                                                          unsigned short* __restrict__ out,
                                                          int n4) {
    int i = blockIdx.x * 256 + threadIdx.x;
    if (i < n4) {
        float4 v = ((const float4*)in)[i];
        ushort4 o;
        o.x = f2h(v.x); o.y = f2h(v.y); o.z = f2h(v.z); o.w = f2h(v.w);
        ((ushort4*)out)[i] = o;
    }
}

// ---------------- 4 x (W [K][N] fp32 -> Wt [N][K] fp16) fused -------------------
__global__ __launch_bounds__(256) void transpose_w_kernel(const float* __restrict__ W0,
                                                          const float* __restrict__ W1,
                                                          const float* __restrict__ W2,
                                                          const float* __restrict__ W3,
                                                          unsigned short* __restrict__ T0,
                                                          unsigned short* __restrict__ T1,
                                                          unsigned short* __restrict__ T2,
                                                          unsigned short* __restrict__ T3) {
    const float* W = blockIdx.z == 0 ? W0 : blockIdx.z == 1 ? W1 : blockIdx.z == 2 ? W2 : W3;
    unsigned short* Wt = blockIdx.z == 0 ? T0 : blockIdx.z == 1 ? T1 : blockIdx.z == 2 ? T2 : T3;
    __shared__ float tile[32][33];
    int x = threadIdx.x;
    int y = threadIdx.y;
    int k0 = blockIdx.y * 32;
    int n0 = blockIdx.x * 32;
    for (int i = 0; i < 4; i++)
        tile[y + 8 * i][x] = W[(size_t)(k0 + y + 8 * i) * D_MODEL + n0 + x];
    __syncthreads();
    for (int i = 0; i < 4; i++)
        Wt[(size_t)(n0 + y + 8 * i) * D_MODEL + k0 + x] = f2h(tile[x][y + 8 * i]);
}

// ---------------- NT GEMM body: C[M][N] = A[M][K] * Bt[N][K]^T ------------------
// MODE 0: fp16 -> Q/K layout [b][h][s][dh], LDS-bounce coalesced stores (×osc)
// MODE 1: fp16 -> V^T layout [b][h][dh][s], LDS-bounce (transposed) stores
// MODE 2: fp32 -> [M][N] direct stores
template<int MODE>
__device__ __forceinline__ void gemm_body(const unsigned short* __restrict__ A,
                                          const unsigned short* __restrict__ Bt,
                                          void* __restrict__ Cout,
                                          int M, int N, int K,
                                          int bx, int by,
                                          unsigned short* smem, float osc) {
    unsigned short* As = smem;             // 128*32 halfs
    unsigned short* Bs = smem + 4096;      // 128*32 halfs
    const int tid  = threadIdx.x;
    const int wave = tid >> 6;
    const int lane = tid & 63;
    const int quad = lane >> 4;
    const int l16  = lane & 15;
    const int wm = (wave >> 1) * 64;
    const int wn = (wave & 1) * 64;
    const int tm = by * 128;
    const int tn = bx * 128;

    const int ci0 = wave * 128 + lane;
    const int row0 = ci0 >> 2, s0 = ci0 & 3;
    const int gc0 = s0 ^ ((row0 >> 1) & 3);
    const int ci1 = ci0 + 64;
    const int row1 = ci1 >> 2, s1 = ci1 & 3;
    const int gc1 = s1 ^ ((row1 >> 1) & 3);

    floatx4 acc[4][4] = {};

    for (int k0 = 0; k0 < K; k0 += 32) {
        __syncthreads();
        gload_lds16(A  + (size_t)(tm + row0) * K + k0 + gc0 * 8, &As[(wave * 2 + 0) * 512]);
        gload_lds16(A  + (size_t)(tm + row1) * K + k0 + gc1 * 8, &As[(wave * 2 + 1) * 512]);
        gload_lds16(Bt + (size_t)(tn + row0) * K + k0 + gc0 * 8, &Bs[(wave * 2 + 0) * 512]);
        gload_lds16(Bt + (size_t)(tn + row1) * K + k0 + gc1 * 8, &Bs[(wave * 2 + 1) * 512]);
        __syncthreads();

        half8 af[4], bf[4];
#pragma unroll
        for (int mi = 0; mi < 4; mi++) {
            int row = wm + mi * 16 + l16;
            af[mi] = *(const half8*)(&As[row * 32 + (quad ^ ((row >> 1) & 3)) * 8]);
        }
#pragma unroll
        for (int ni = 0; ni < 4; ni++) {
            int row = wn + ni * 16 + l16;
            bf[ni] = *(const half8*)(&Bs[row * 32 + (quad ^ ((row >> 1) & 3)) * 8]);
        }
#pragma unroll
        for (int mi = 0; mi < 4; mi++)
#pragma unroll
            for (int ni = 0; ni < 4; ni++)
                acc[mi][ni] = __builtin_amdgcn_mfma_f32_16x16x32_f16(af[mi], bf[ni], acc[mi][ni], 0, 0, 0);
    }

    if (MODE == 2) {
#pragma unroll
        for (int mi = 0; mi < 4; mi++)
#pragma unroll
            for (int ni = 0; ni < 4; ni++)
#pragma unroll
                for (int r = 0; r < 4; r++) {
                    int row = tm + wm + mi * 16 + quad * 4 + r;
                    int col = tn + wn + ni * 16 + l16;
                    ((float*)Cout)[(size_t)row * N + col] = acc[mi][ni][r];
                }
        return;
    }

    __syncthreads();   // all waves done reading As/Bs
    if (MODE == 0) {
#pragma unroll
        for (int mi = 0; mi < 4; mi++)
#pragma unroll
            for (int ni = 0; ni < 4; ni++) {
                int col = wn + ni * 16 + l16;
                int cc  = col >> 4;
                int cil = col & 15;
#pragma unroll
                for (int r = 0; r < 4; r++) {
                    int row = wm + mi * 16 + quad * 4 + r;
                    smem[row * 128 + ((cc ^ ((row >> 2) & 7)) << 4) + cil] = f2h(acc[mi][ni][r] * osc);
                }
            }
        __syncthreads();
        unsigned short* O = (unsigned short*)Cout;
#pragma unroll
        for (int j = 0; j < 8; j++) {
            int vid = tid + j * 256;
            int row = vid >> 4, vv = vid & 15;
            int cc = vv >> 1, hf = vv & 1;
            uint4 v = *(const uint4*)(&smem[row * 128 + ((cc ^ ((row >> 2) & 7)) << 4) + hf * 8]);
            int grow = tm + row;
            int b = grow >> 11, s = grow & 2047;
            int n = tn + vv * 8;
            int h = n >> 6, dh = n & 63;
            *(uint4*)(O + (((size_t)(b * NH + h) * S_LEN + s) * DHEAD + dh)) = v;
        }
    } else {
#pragma unroll
        for (int mi = 0; mi < 4; mi++)
#pragma unroll
            for (int ni = 0; ni < 4; ni++) {
                int col = wn + ni * 16 + l16;
                int sw  = (col >> 2) & 7;
#pragma unroll
                for (int r = 0; r < 4; r++) {
                    int row = wm + mi * 16 + quad * 4 + r;
                    smem[col * 128 + (((row >> 4) ^ sw) << 4) + (row & 15)] = f2h(acc[mi][ni][r]);
                }
            }
        __syncthreads();
        unsigned short* O = (unsigned short*)Cout;
        int b = tm >> 11;
        int sbase = tm & 2047;
#pragma unroll
        for (int j = 0; j < 8; j++) {
            int vid = tid + j * 256;
            int colr = vid >> 4, vv = vid & 15;
            int rc = vv >> 1, hf = vv & 1;
            uint4 v = *(const uint4*)(&smem[colr * 128 + ((rc ^ ((colr >> 2) & 7)) << 4) + hf * 8]);
            int n = tn + colr;
            int h = n >> 6, dh = n & 63;
            *(uint4*)(O + (((size_t)(b * NH + h) * DHEAD + dh) * S_LEN + sbase + vv * 8)) = v;
        }
    }
}

// fused QKV projection: z=0 Q (mode0, ×EXP2SCALE), z=1 K (mode0), z=2 V (mode1)
__global__ __launch_bounds__(256) void qkv_gemm_kernel(const unsigned short* __restrict__ A,
                                                       const unsigned short* __restrict__ Wq,
                                                       const unsigned short* __restrict__ Wk,
                                                       const unsigned short* __restrict__ Wv,
                                                       unsigned short* __restrict__ Qo,
                                                       unsigned short* __restrict__ Ko,
                                                       unsigned short* __restrict__ Vo) {
    __shared__ unsigned short smem[128 * 128];
    const int z = blockIdx.z;
    if (z == 2)
        gemm_body<1>(A, Wv, Vo, BATCH * S_LEN, D_MODEL, D_MODEL, blockIdx.x, blockIdx.y, smem, 1.f);
    else
        gemm_body<0>(A, z == 0 ? Wq : Wk, z == 0 ? Qo : Ko,
                     BATCH * S_LEN, D_MODEL, D_MODEL, blockIdx.x, blockIdx.y, smem,
                     z == 0 ? EXP2SCALE : 1.f);
}

__global__ __launch_bounds__(256) void out_gemm_kernel(const unsigned short* __restrict__ A,
                                                       const unsigned short* __restrict__ Bt,
                                                       float* __restrict__ C) {
    __shared__ unsigned short smem[128 * 128];
    gemm_body<2>(A, Bt, C, BATCH * S_LEN, D_MODEL, D_MODEL, blockIdx.x, blockIdx.y, smem, 1.f);
}

// ---------------- Flash attention v3 (causal) -----------------------------------
// Q (pre-scaled by EXP2SCALE), K: [b][h][s][dh] fp16 ; Vt: [b][h][dh][s] fp16
// ctx: [b][s][h*dh] fp16.
// Block = 256 threads / 4 waves; block owns q-tile t (128 rows); wave owns 32 q
// (2 fragment sets). O^T orientation: acc cols = q = l16 -> lane-local m/l/alpha.
// Grid (16, NH, B) = 1024 blocks; per-block rounds = 2t+2 (dynamic balancing).
__global__ __launch_bounds__(256, 4) void attn_kernel(const unsigned short* __restrict__ Q,
                                                      const unsigned short* __restrict__ K,
                                                      const unsigned short* __restrict__ Vt,
                                                      unsigned short* __restrict__ ctx) {
    __shared__ unsigned short smem[17408];    // Ks 4096 | Vs 4096 | Ps 4*32*72
    unsigned short* Ks = smem;
    unsigned short* Vs = smem + 4096;
    unsigned short* Ps = smem + 8192;
    const int tid  = threadIdx.x;
    const int wave = tid >> 6;
    const int lane = tid & 63;
    const int quad = lane >> 4;
    const int l16  = lane & 15;
    const int t = blockIdx.x;
    const int h = blockIdx.y;
    const int b = blockIdx.z;
    const size_t head = (size_t)(b * NH + h) * (S_LEN * DHEAD);

    const int rounds = 2 * t + 2;
    const int dk = 2 * t + (wave >> 1);          // wave's diagonal chunk
    const int qg0 = t * 128 + wave * 32 + l16;   // set0 softmax q row (set1 = +16)

    // Q B-fragments (global layout == frag layout), Q pre-scaled by EXP2SCALE
    half8 qf[2][2];
#pragma unroll
    for (int s = 0; s < 2; s++)
#pragma unroll
        for (int ks = 0; ks < 2; ks++)
            qf[s][ks] = *(const half8*)(Q + head + (size_t)(qg0 + s * 16) * DHEAD + ks * 32 + quad * 8);

    // staging geometry: 512 chunks per 64x64 tile, 2 issues per thread
    const int r0 = tid >> 3,        g0 = (tid & 7) ^ (r0 & 7);
    const int c1 = tid + 256;
    const int r1 = c1 >> 3,         g1 = (c1 & 7) ^ (r1 & 7);
    const unsigned short* pK0 = K  + head + (size_t)r0 * DHEAD + g0 * 8;
    const unsigned short* pK1 = K  + head + (size_t)r1 * DHEAD + g1 * 8;
    const unsigned short* pV0 = Vt + head + (size_t)r0 * S_LEN + g0 * 8;
    const unsigned short* pV1 = Vt + head + (size_t)r1 * S_LEN + g1 * 8;

    // hoisted LDS read bases (half indices): row l16, swizzled chunk
    const int akb0 = l16 * 64 + (( quad     ) ^ (l16 & 7)) * 8;   // ks=0
    const int akb1 = l16 * 64 + (((4 | quad)) ^ (l16 & 7)) * 8;   // ks=1
    const int psr  = wave * 2304 + l16 * 72;                      // Ps set0 row base

    floatx4 acc0[4] = {}, acc1[4] = {};
    float m0 = -3.0e38f, l0 = 0.f, m1 = -3.0e38f, l1 = 0.f;

    for (int c = 0; c < rounds; c++) {
        __syncthreads();
        gload_lds16(pK0, Ks + wave * 512);
        gload_lds16(pK1, Ks + 2048 + wave * 512);
        gload_lds16(pV0, Vs + wave * 512);
        gload_lds16(pV1, Vs + 2048 + wave * 512);
        pK0 += 64 * DHEAD; pK1 += 64 * DHEAD; pV0 += 64; pV1 += 64;
        __syncthreads();

        if (c > dk) continue;

        // S^T = K Q^T for both q-sets; sc C-layout: col=q=l16, row=kk=mk*16+quad*4+r
        floatx4 sc0[4] = {}, sc1[4] = {};
#pragma unroll
        for (int ks = 0; ks < 2; ks++) {
            const int ab = ks ? akb1 : akb0;
#pragma unroll
            for (int mk = 0; mk < 4; mk++) {
                half8 ak = *(const half8*)(&Ks[mk * 1024 + ab]);
                sc0[mk] = __builtin_amdgcn_mfma_f32_16x16x32_f16(ak, qf[0][ks], sc0[mk], 0, 0, 0);
                sc1[mk] = __builtin_amdgcn_mfma_f32_16x16x32_f16(ak, qf[1][ks], sc1[mk], 0, 0, 0);
            }
        }

        const bool diag = (c == dk);

#define SOFTMAX_SET(sc, m_s, l_s, acc, qg, setofs)                                \
        {                                                                         \
            if (diag) {                                                           \
                int rel = (qg) - c * 64 - quad * 4;                               \
                _Pragma("unroll")                                                 \
                for (int mk = 0; mk < 4; mk++)                                    \
                    _Pragma("unroll")                                             \
                    for (int r = 0; r < 4; r++)                                   \
                        if (mk * 16 + r > rel) sc[mk][r] = -3.0e38f;              \
            }                                                                     \
            float mx = sc[0][0];                                                  \
            _Pragma("unroll")                                                     \
            for (int mk = 0; mk < 4; mk++)                                        \
                _Pragma("unroll")                                                 \
                for (int r = 0; r < 4; r++)                                       \
                    if (mk || r) mx = fmaxf(mx, sc[mk][r]);                       \
            mx = fmaxf(mx, __shfl_xor(mx, 16, 64));                               \
            mx = fmaxf(mx, __shfl_xor(mx, 32, 64));                               \
            float mn = fmaxf(m_s, mx);                                            \
            float al = exp2f(m_s - mn);                                           \
            m_s = mn;                                                             \
            float rs = 0.f;                                                       \
            _Pragma("unroll")                                                     \
            for (int mk = 0; mk < 4; mk++)                                        \
                _Pragma("unroll")                                                 \
                for (int r = 0; r < 4; r++) {                                     \
                    float e = exp2f(sc[mk][r] - mn);                               \
                    sc[mk][r] = e;                                                 \
                    rs += e;                                                       \
                }                                                                 \
            rs += __shfl_xor(rs, 16, 64);                                         \
            rs += __shfl_xor(rs, 32, 64);                                         \
            l_s = l_s * al + rs;                                                  \
            _Pragma("unroll")                                                     \
            for (int db = 0; db < 4; db++)                                        \
                _Pragma("unroll")                                                 \
                for (int r = 0; r < 4; r++) acc[db][r] *= al;                     \
            _Pragma("unroll")                                                     \
            for (int mk = 0; mk < 4; mk++) {                                      \
                uint2 u;                                                          \
                u.x = pk2(sc[mk][0], sc[mk][1]);                                  \
                u.y = pk2(sc[mk][2], sc[mk][3]);                                  \
                *(uint2*)(&Ps[psr + (setofs) + mk * 16 + quad * 4]) = u;          \
            }                                                                     \
        }

        SOFTMAX_SET(sc0, m0, l0, acc0, qg0,    0)
        SOFTMAX_SET(sc1, m1, l1, acc1, qg0+16, 1152)
#undef SOFTMAX_SET

        // O^T += V^T P^T : A = Vs rows (dh), B = own-wave Ps rows (q)
#pragma unroll
        for (int ks = 0; ks < 2; ks++) {
            const int ab = ks ? akb1 : akb0;
            half8 bp0 = *(const half8*)(&Ps[psr        + ks * 32 + quad * 8]);
            half8 bp1 = *(const half8*)(&Ps[psr + 1152 + ks * 32 + quad * 8]);
#pragma unroll
            for (int db = 0; db < 4; db++) {
                half8 av = *(const half8*)(&Vs[db * 1024 + ab]);
                acc0[db] = __builtin_amdgcn_mfma_f32_16x16x32_f16(av, bp0, acc0[db], 0, 0, 0);
                acc1[db] = __builtin_amdgcn_mfma_f32_16x16x32_f16(av, bp1, acc1[db], 0, 0, 0);
            }
        }
    }

    // ---- epilogue: O^T -> LDS bounce -> coalesced ctx stores ----------------
    __syncthreads();   // everyone done with Ks/Vs
#pragma unroll
    for (int s = 0; s < 2; s++) {
        float inv = 1.f / (s ? l1 : l0);
        int qrow = wave * 32 + s * 16 + l16;
        floatx4* ac = s ? acc1 : acc0;
#pragma unroll
        for (int db = 0; db < 4; db++) {
            uint2 u;
            u.x = pk2(ac[db][0] * inv, ac[db][1] * inv);
            u.y = pk2(ac[db][2] * inv, ac[db][3] * inv);
            int chunk = db * 2 + (quad >> 1);
            int sw = chunk ^ (qrow & 7);
            *(uint2*)(&smem[qrow * 64 + sw * 8 + (quad & 1) * 4]) = u;
        }
    }
    __syncthreads();
#pragma unroll
    for (int j = 0; j < 4; j++) {
        int vid = j * 256 + tid;
        int q = vid >> 3, slot = vid & 7;
        uint4 v = *(const uint4*)(&smem[q * 64 + slot * 8]);
        int dhc = slot ^ (q & 7);
        *(uint4*)(ctx + ((size_t)b * S_LEN + t * 128 + q) * D_MODEL + h * DHEAD + dhc * 8) = v;
    }
}

extern "C" void kernel_launch(void* const* d_in, const int* in_sizes, int n_in,
                              void* d_out, int out_size, void* d_ws, size_t ws_size,
                              hipStream_t stream) {
    const float* x  = (const float*)d_in[0];
    const float* Wq = (const float*)d_in[1];
    const float* Wk = (const float*)d_in[2];
    const float* Wv = (const float*)d_in[3];
    const float* Wo = (const float*)d_in[4];

    char* ws = (char*)d_ws;
    unsigned short* Xh   = (unsigned short*)(ws + 0);            // 16 MB
    unsigned short* Wqt  = (unsigned short*)(ws + 16777216);     // 2 MB
    unsigned short* Wkt  = (unsigned short*)(ws + 18874368);     // 2 MB
    unsigned short* Wvt  = (unsigned short*)(ws + 20971520);     // 2 MB
    unsigned short* Wot  = (unsigned short*)(ws + 23068672);     // 2 MB
    unsigned short* Qh   = (unsigned short*)(ws + 25165824);     // 16 MB
    unsigned short* Kh   = (unsigned short*)(ws + 41943040);     // 16 MB
    unsigned short* Vth  = (unsigned short*)(ws + 58720256);     // 16 MB
    unsigned short* ctxh = (unsigned short*)(ws + 75497472);     // 16 MB

    const int M = BATCH * S_LEN;   // 8192

    convert_f2h_kernel<<<(M * D_MODEL / 4 + 255) / 256, 256, 0, stream>>>(x, Xh, M * D_MODEL / 4);
    transpose_w_kernel<<<dim3(32, 32, 4), dim3(32, 8), 0, stream>>>(Wq, Wk, Wv, Wo, Wqt, Wkt, Wvt, Wot);

    qkv_gemm_kernel<<<dim3(8, 64, 3), 256, 0, stream>>>(Xh, Wqt, Wkt, Wvt, Qh, Kh, Vth);

    attn_kernel<<<dim3(16, NH, BATCH), 256, 0, stream>>>(Qh, Kh, Vth, ctxh);

    out_gemm_kernel<<<dim3(8, 64), 256, 0, stream>>>(ctxh, Wot, (float*)d_out);
}

// Round 7
// 276.694 us; speedup vs baseline: 1.1551x; 1.1551x over previous
//
#include <hip/hip_runtime.h>

#define S_LEN 2048
#define D_MODEL 1024
#define NH 16
#define DHEAD 64
#define BATCH 4

typedef _Float16 half8 __attribute__((ext_vector_type(8)));
typedef __fp16 fp16x2 __attribute__((ext_vector_type(2)));
typedef float floatx4 __attribute__((ext_vector_type(4)));

#define EXP2SCALE 0.1803368801111244f   // (1/sqrt(64)) * log2(e), folded into Q projection

__device__ __forceinline__ unsigned short f2h(float f) {
    _Float16 h = (_Float16)f;
    return __builtin_bit_cast(unsigned short, h);
}

// pack two floats -> 2x fp16 (RTZ) as uint bits
__device__ __forceinline__ unsigned int pk2(float a, float b) {
    fp16x2 p = __builtin_amdgcn_cvt_pkrtz(a, b);
    return __builtin_bit_cast(unsigned int, p);
}

// async global->LDS, 16B per lane; lds dest = wave-uniform base + lane*16
__device__ __forceinline__ void gload_lds16(const unsigned short* g, unsigned short* l) {
    __builtin_amdgcn_global_load_lds(
        (const __attribute__((address_space(1))) void*)g,
        (__attribute__((address_space(3))) void*)l,
        16, 0, 0);
}

// ---------------- conversion: fp32 -> fp16 bits ---------------------------------
__global__ __launch_bounds__(256) void convert_f2h_kernel(const float* __restrict__ in,
                                                          unsigned short* __restrict__ out,
                                                          int n4) {
    int i = blockIdx.x * 256 + threadIdx.x;
    if (i < n4) {
        float4 v = ((const float4*)in)[i];
        ushort4 o;
        o.x = f2h(v.x); o.y = f2h(v.y); o.z = f2h(v.z); o.w = f2h(v.w);
        ((ushort4*)out)[i] = o;
    }
}

// ---------------- 4 x (W [K][N] fp32 -> Wt [N][K] fp16) fused -------------------
__global__ __launch_bounds__(256) void transpose_w_kernel(const float* __restrict__ W0,
                                                          const float* __restrict__ W1,
                                                          const float* __restrict__ W2,
                                                          const float* __restrict__ W3,
                                                          unsigned short* __restrict__ T0,
                                                          unsigned short* __restrict__ T1,
                                                          unsigned short* __restrict__ T2,
                                                          unsigned short* __restrict__ T3) {
    const float* W = blockIdx.z == 0 ? W0 : blockIdx.z == 1 ? W1 : blockIdx.z == 2 ? W2 : W3;
    unsigned short* Wt = blockIdx.z == 0 ? T0 : blockIdx.z == 1 ? T1 : blockIdx.z == 2 ? T2 : T3;
    __shared__ float tile[32][33];
    int x = threadIdx.x;
    int y = threadIdx.y;
    int k0 = blockIdx.y * 32;
    int n0 = blockIdx.x * 32;
    for (int i = 0; i < 4; i++)
        tile[y + 8 * i][x] = W[(size_t)(k0 + y + 8 * i) * D_MODEL + n0 + x];
    __syncthreads();
    for (int i = 0; i < 4; i++)
        Wt[(size_t)(n0 + y + 8 * i) * D_MODEL + k0 + x] = f2h(tile[x][y + 8 * i]);
}

// ---------------- NT GEMM body: C[M][N] = A[M][K] * Bt[N][K]^T ------------------
// MODE 0: fp16 -> Q/K layout [b][h][s][dh], LDS-bounce coalesced stores (×osc)
// MODE 1: fp16 -> V^T layout [b][h][dh][s], LDS-bounce (transposed) stores
// MODE 2: fp32 -> [M][N] direct stores
template<int MODE>
__device__ __forceinline__ void gemm_body(const unsigned short* __restrict__ A,
                                          const unsigned short* __restrict__ Bt,
                                          void* __restrict__ Cout,
                                          int M, int N, int K,
                                          int bx, int by,
                                          unsigned short* smem, float osc) {
    unsigned short* As = smem;             // 128*32 halfs
    unsigned short* Bs = smem + 4096;      // 128*32 halfs
    const int tid  = threadIdx.x;
    const int wave = tid >> 6;
    const int lane = tid & 63;
    const int quad = lane >> 4;
    const int l16  = lane & 15;
    const int wm = (wave >> 1) * 64;
    const int wn = (wave & 1) * 64;
    const int tm = by * 128;
    const int tn = bx * 128;

    const int ci0 = wave * 128 + lane;
    const int row0 = ci0 >> 2, s0 = ci0 & 3;
    const int gc0 = s0 ^ ((row0 >> 1) & 3);
    const int ci1 = ci0 + 64;
    const int row1 = ci1 >> 2, s1 = ci1 & 3;
    const int gc1 = s1 ^ ((row1 >> 1) & 3);

    floatx4 acc[4][4] = {};

    for (int k0 = 0; k0 < K; k0 += 32) {
        __syncthreads();
        gload_lds16(A  + (size_t)(tm + row0) * K + k0 + gc0 * 8, &As[(wave * 2 + 0) * 512]);
        gload_lds16(A  + (size_t)(tm + row1) * K + k0 + gc1 * 8, &As[(wave * 2 + 1) * 512]);
        gload_lds16(Bt + (size_t)(tn + row0) * K + k0 + gc0 * 8, &Bs[(wave * 2 + 0) * 512]);
        gload_lds16(Bt + (size_t)(tn + row1) * K + k0 + gc1 * 8, &Bs[(wave * 2 + 1) * 512]);
        __syncthreads();

        half8 af[4], bf[4];
#pragma unroll
        for (int mi = 0; mi < 4; mi++) {
            int row = wm + mi * 16 + l16;
            af[mi] = *(const half8*)(&As[row * 32 + (quad ^ ((row >> 1) & 3)) * 8]);
        }
#pragma unroll
        for (int ni = 0; ni < 4; ni++) {
            int row = wn + ni * 16 + l16;
            bf[ni] = *(const half8*)(&Bs[row * 32 + (quad ^ ((row >> 1) & 3)) * 8]);
        }
#pragma unroll
        for (int mi = 0; mi < 4; mi++)
#pragma unroll
            for (int ni = 0; ni < 4; ni++)
                acc[mi][ni] = __builtin_amdgcn_mfma_f32_16x16x32_f16(af[mi], bf[ni], acc[mi][ni], 0, 0, 0);
    }

    if (MODE == 2) {
#pragma unroll
        for (int mi = 0; mi < 4; mi++)
#pragma unroll
            for (int ni = 0; ni < 4; ni++)
#pragma unroll
                for (int r = 0; r < 4; r++) {
                    int row = tm + wm + mi * 16 + quad * 4 + r;
                    int col = tn + wn + ni * 16 + l16;
                    ((float*)Cout)[(size_t)row * N + col] = acc[mi][ni][r];
                }
        return;
    }

    __syncthreads();   // all waves done reading As/Bs
    if (MODE == 0) {
#pragma unroll
        for (int mi = 0; mi < 4; mi++)
#pragma unroll
            for (int ni = 0; ni < 4; ni++) {
                int col = wn + ni * 16 + l16;
                int cc  = col >> 4;
                int cil = col & 15;
#pragma unroll
                for (int r = 0; r < 4; r++) {
                    int row = wm + mi * 16 + quad * 4 + r;
                    smem[row * 128 + ((cc ^ ((row >> 2) & 7)) << 4) + cil] = f2h(acc[mi][ni][r] * osc);
                }
            }
        __syncthreads();
        unsigned short* O = (unsigned short*)Cout;
#pragma unroll
        for (int j = 0; j < 8; j++) {
            int vid = tid + j * 256;
            int row = vid >> 4, vv = vid & 15;
            int cc = vv >> 1, hf = vv & 1;
            uint4 v = *(const uint4*)(&smem[row * 128 + ((cc ^ ((row >> 2) & 7)) << 4) + hf * 8]);
            int grow = tm + row;
            int b = grow >> 11, s = grow & 2047;
            int n = tn + vv * 8;
            int h = n >> 6, dh = n & 63;
            *(uint4*)(O + (((size_t)(b * NH + h) * S_LEN + s) * DHEAD + dh)) = v;
        }
    } else {
#pragma unroll
        for (int mi = 0; mi < 4; mi++)
#pragma unroll
            for (int ni = 0; ni < 4; ni++) {
                int col = wn + ni * 16 + l16;
                int sw  = (col >> 2) & 7;
#pragma unroll
                for (int r = 0; r < 4; r++) {
                    int row = wm + mi * 16 + quad * 4 + r;
                    smem[col * 128 + (((row >> 4) ^ sw) << 4) + (row & 15)] = f2h(acc[mi][ni][r]);
                }
            }
        __syncthreads();
        unsigned short* O = (unsigned short*)Cout;
        int b = tm >> 11;
        int sbase = tm & 2047;
#pragma unroll
        for (int j = 0; j < 8; j++) {
            int vid = tid + j * 256;
            int colr = vid >> 4, vv = vid & 15;
            int rc = vv >> 1, hf = vv & 1;
            uint4 v = *(const uint4*)(&smem[colr * 128 + ((rc ^ ((colr >> 2) & 7)) << 4) + hf * 8]);
            int n = tn + colr;
            int h = n >> 6, dh = n & 63;
            *(uint4*)(O + (((size_t)(b * NH + h) * DHEAD + dh) * S_LEN + sbase + vv * 8)) = v;
        }
    }
}

// fused QKV projection: z=0 Q (mode0, ×EXP2SCALE), z=1 K (mode0), z=2 V (mode1)
__global__ __launch_bounds__(256) void qkv_gemm_kernel(const unsigned short* __restrict__ A,
                                                       const unsigned short* __restrict__ Wq,
                                                       const unsigned short* __restrict__ Wk,
                                                       const unsigned short* __restrict__ Wv,
                                                       unsigned short* __restrict__ Qo,
                                                       unsigned short* __restrict__ Ko,
                                                       unsigned short* __restrict__ Vo) {
    __shared__ unsigned short smem[128 * 128];
    const int z = blockIdx.z;
    if (z == 2)
        gemm_body<1>(A, Wv, Vo, BATCH * S_LEN, D_MODEL, D_MODEL, blockIdx.x, blockIdx.y, smem, 1.f);
    else
        gemm_body<0>(A, z == 0 ? Wq : Wk, z == 0 ? Qo : Ko,
                     BATCH * S_LEN, D_MODEL, D_MODEL, blockIdx.x, blockIdx.y, smem,
                     z == 0 ? EXP2SCALE : 1.f);
}

__global__ __launch_bounds__(256) void out_gemm_kernel(const unsigned short* __restrict__ A,
                                                       const unsigned short* __restrict__ Bt,
                                                       float* __restrict__ C) {
    __shared__ unsigned short smem[128 * 128];
    gemm_body<2>(A, Bt, C, BATCH * S_LEN, D_MODEL, D_MODEL, blockIdx.x, blockIdx.y, smem, 1.f);
}

// ---------------- Flash attention v4 (causal), dual-tile blocks -----------------
// Q (pre-scaled), K: [b][h][s][dh] fp16 ; Vt: [b][h][dh][s] fp16 ; ctx fp16.
// 512 threads / 8 waves. Waves 0-3 own q-tile ta=bx (128 rows, 32 q/wave),
// waves 4-7 own tb=15-bx. One staging loop of 2*tb+2 rounds serves both
// (ta<=7<=tb so A's K-range is a subset). Uniform compute across blocks.
// Grid (8, NH, B) = 512 blocks = 2/CU, 16 waves/CU.
__global__ __launch_bounds__(512, 4) void attn_kernel(const unsigned short* __restrict__ Q,
                                                      const unsigned short* __restrict__ K,
                                                      const unsigned short* __restrict__ Vt,
                                                      unsigned short* __restrict__ ctx) {
    __shared__ unsigned short smem[26624];    // Ks 4096 | Vs 4096 | Ps 8*2304 halfs
    unsigned short* Ks = smem;
    unsigned short* Vs = smem + 4096;
    unsigned short* Ps = smem + 8192;
    const int tid  = threadIdx.x;
    const int wave = tid >> 6;
    const int wg   = wave >> 2;        // 0 = tile A, 1 = tile B
    const int wv   = wave & 3;         // wave within group
    const int lane = tid & 63;
    const int quad = lane >> 4;
    const int l16  = lane & 15;
    const int bx = blockIdx.x;         // 0..7
    const int h  = blockIdx.y;
    const int b  = blockIdx.z;
    const size_t head = (size_t)(b * NH + h) * (S_LEN * DHEAD);

    const int ta = bx, tb = 15 - bx;
    const int tw = wg ? tb : ta;                 // this wave's q-tile
    const int rounds = 2 * tb + 2;               // covers both tiles' K-ranges
    const int dk  = 2 * tw + (wv >> 1);          // wave's diagonal chunk
    const int qg0 = tw * 128 + wv * 32 + l16;    // set0 softmax q row (set1 = +16)

    // Q B-fragments (global layout == frag layout), Q pre-scaled by EXP2SCALE
    half8 qf[2][2];
#pragma unroll
    for (int s = 0; s < 2; s++)
#pragma unroll
        for (int ks = 0; ks < 2; ks++)
            qf[s][ks] = *(const half8*)(Q + head + (size_t)(qg0 + s * 16) * DHEAD + ks * 32 + quad * 8);

    // staging: 512 threads x 16B = one full 64x64 tile per array per round
    const int r0 = tid >> 3;
    const int g0 = (tid & 7) ^ (r0 & 7);
    const unsigned short* pK = K  + head + (size_t)r0 * DHEAD + g0 * 8;
    const unsigned short* pV = Vt + head + (size_t)r0 * S_LEN + g0 * 8;

    // hoisted LDS read bases (half indices)
    const int akb0 = l16 * 64 + ((quad    ) ^ (l16 & 7)) * 8;   // ks=0
    const int akb1 = l16 * 64 + ((4 | quad) ^ (l16 & 7)) * 8;   // ks=1
    const int psr  = wave * 2304 + l16 * 72;                    // Ps set0 row base

    floatx4 acc0[4] = {}, acc1[4] = {};
    float m0 = -3.0e38f, l0 = 0.f, m1 = -3.0e38f, l1 = 0.f;

    for (int c = 0; c < rounds; c++) {
        __syncthreads();
        gload_lds16(pK, Ks + wave * 512);
        gload_lds16(pV, Vs + wave * 512);
        pK += 64 * DHEAD; pV += 64;
        __syncthreads();

        if (c > dk) continue;

        // S^T = K Q^T ; sc C-layout: col=q=l16, row=kk=mk*16+quad*4+r
        floatx4 sc0[4] = {}, sc1[4] = {};
#pragma unroll
        for (int ks = 0; ks < 2; ks++) {
            const int ab = ks ? akb1 : akb0;
#pragma unroll
            for (int mk = 0; mk < 4; mk++) {
                half8 ak = *(const half8*)(&Ks[mk * 1024 + ab]);
                sc0[mk] = __builtin_amdgcn_mfma_f32_16x16x32_f16(ak, qf[0][ks], sc0[mk], 0, 0, 0);
                sc1[mk] = __builtin_amdgcn_mfma_f32_16x16x32_f16(ak, qf[1][ks], sc1[mk], 0, 0, 0);
            }
        }

        const bool diag = (c == dk);

#define SOFTMAX_SET(sc, m_s, l_s, acc, qg, setofs)                                \
        {                                                                         \
            if (diag) {                                                           \
                int rel = (qg) - c * 64 - quad * 4;                               \
                _Pragma("unroll")                                                 \
                for (int mk = 0; mk < 4; mk++)                                    \
                    _Pragma("unroll")                                             \
                    for (int r = 0; r < 4; r++)                                   \
                        if (mk * 16 + r > rel) sc[mk][r] = -3.0e38f;              \
            }                                                                     \
            float mx = sc[0][0];                                                  \
            _Pragma("unroll")                                                     \
            for (int mk = 0; mk < 4; mk++)                                        \
                _Pragma("unroll")                                                 \
                for (int r = 0; r < 4; r++)                                       \
                    if (mk || r) mx = fmaxf(mx, sc[mk][r]);                       \
            mx = fmaxf(mx, __shfl_xor(mx, 16, 64));                               \
            mx = fmaxf(mx, __shfl_xor(mx, 32, 64));                               \
            float mn = fmaxf(m_s, mx);                                            \
            float al = exp2f(m_s - mn);                                           \
            m_s = mn;                                                             \
            float rs = 0.f;                                                       \
            _Pragma("unroll")                                                     \
            for (int mk = 0; mk < 4; mk++)                                        \
                _Pragma("unroll")                                                 \
                for (int r = 0; r < 4; r++) {                                     \
                    float e = exp2f(sc[mk][r] - mn);                               \
                    sc[mk][r] = e;                                                 \
                    rs += e;                                                       \
                }                                                                 \
            rs += __shfl_xor(rs, 16, 64);                                         \
            rs += __shfl_xor(rs, 32, 64);                                         \
            l_s = l_s * al + rs;                                                  \
            _Pragma("unroll")                                                     \
            for (int db = 0; db < 4; db++)                                        \
                _Pragma("unroll")                                                 \
                for (int r = 0; r < 4; r++) acc[db][r] *= al;                     \
            _Pragma("unroll")                                                     \
            for (int mk = 0; mk < 4; mk++) {                                      \
                uint2 u;                                                          \
                u.x = pk2(sc[mk][0], sc[mk][1]);                                  \
                u.y = pk2(sc[mk][2], sc[mk][3]);                                  \
                *(uint2*)(&Ps[psr + (setofs) + mk * 16 + quad * 4]) = u;          \
            }                                                                     \
        }

        SOFTMAX_SET(sc0, m0, l0, acc0, qg0,      0)
        SOFTMAX_SET(sc1, m1, l1, acc1, qg0 + 16, 1152)
#undef SOFTMAX_SET

        // O^T += V^T P^T : A = Vs rows (dh), B = own-wave Ps rows (q)
#pragma unroll
        for (int ks = 0; ks < 2; ks++) {
            const int ab = ks ? akb1 : akb0;
            half8 bp0 = *(const half8*)(&Ps[psr        + ks * 32 + quad * 8]);
            half8 bp1 = *(const half8*)(&Ps[psr + 1152 + ks * 32 + quad * 8]);
#pragma unroll
            for (int db = 0; db < 4; db++) {
                half8 av = *(const half8*)(&Vs[db * 1024 + ab]);
                acc0[db] = __builtin_amdgcn_mfma_f32_16x16x32_f16(av, bp0, acc0[db], 0, 0, 0);
                acc1[db] = __builtin_amdgcn_mfma_f32_16x16x32_f16(av, bp1, acc1[db], 0, 0, 0);
            }
        }
    }

    // ---- epilogue: O^T -> LDS bounce (256 rows x 64 halfs) -> coalesced stores --
    __syncthreads();   // everyone done with Ks/Vs/Ps
#pragma unroll
    for (int s = 0; s < 2; s++) {
        float inv = 1.f / (s ? l1 : l0);
        int qrow = wg * 128 + wv * 32 + s * 16 + l16;   // 0..255 local
        floatx4* ac = s ? acc1 : acc0;
#pragma unroll
        for (int db = 0; db < 4; db++) {
            uint2 u;
            u.x = pk2(ac[db][0] * inv, ac[db][1] * inv);
            u.y = pk2(ac[db][2] * inv, ac[db][3] * inv);
            int chunk = db * 2 + (quad >> 1);
            int sw = chunk ^ (qrow & 7);
            *(uint2*)(&smem[qrow * 64 + sw * 8 + (quad & 1) * 4]) = u;
        }
    }
    __syncthreads();
#pragma unroll
    for (int j = 0; j < 4; j++) {
        int vid = j * 512 + tid;              // 0..2047
        int ql = vid >> 3, slot = vid & 7;    // ql: 0..255 local row
        uint4 v = *(const uint4*)(&smem[ql * 64 + slot * 8]);
        int dhc = slot ^ (ql & 7);
        int q = (ql < 128 ? ta * 128 : tb * 128 - 128) + ql;
        *(uint4*)(ctx + ((size_t)b * S_LEN + q) * D_MODEL + h * DHEAD + dhc * 8) = v;
    }
}

extern "C" void kernel_launch(void* const* d_in, const int* in_sizes, int n_in,
                              void* d_out, int out_size, void* d_ws, size_t ws_size,
                              hipStream_t stream) {
    const float* x  = (const float*)d_in[0];
    const float* Wq = (const float*)d_in[1];
    const float* Wk = (const float*)d_in[2];
    const float* Wv = (const float*)d_in[3];
    const float* Wo = (const float*)d_in[4];

    char* ws = (char*)d_ws;
    unsigned short* Xh   = (unsigned short*)(ws + 0);            // 16 MB
    unsigned short* Wqt  = (unsigned short*)(ws + 16777216);     // 2 MB
    unsigned short* Wkt  = (unsigned short*)(ws + 18874368);     // 2 MB
    unsigned short* Wvt  = (unsigned short*)(ws + 20971520);     // 2 MB
    unsigned short* Wot  = (unsigned short*)(ws + 23068672);     // 2 MB
    unsigned short* Qh   = (unsigned short*)(ws + 25165824);     // 16 MB
    unsigned short* Kh   = (unsigned short*)(ws + 41943040);     // 16 MB
    unsigned short* Vth  = (unsigned short*)(ws + 58720256);     // 16 MB
    unsigned short* ctxh = (unsigned short*)(ws + 75497472);     // 16 MB

    const int M = BATCH * S_LEN;   // 8192

    convert_f2h_kernel<<<(M * D_MODEL / 4 + 255) / 256, 256, 0, stream>>>(x, Xh, M * D_MODEL / 4);
    transpose_w_kernel<<<dim3(32, 32, 4), dim3(32, 8), 0, stream>>>(Wq, Wk, Wv, Wo, Wqt, Wkt, Wvt, Wot);

    qkv_gemm_kernel<<<dim3(8, 64, 3), 256, 0, stream>>>(Xh, Wqt, Wkt, Wvt, Qh, Kh, Vth);

    attn_kernel<<<dim3(8, NH, BATCH), 512, 0, stream>>>(Qh, Kh, Vth, ctxh);

    out_gemm_kernel<<<dim3(8, 64), 256, 0, stream>>>(ctxh, Wot, (float*)d_out);
}

// Round 8
// 258.440 us; speedup vs baseline: 1.2367x; 1.0706x over previous
//
#include <hip/hip_runtime.h>

#define S_LEN 2048
#define D_MODEL 1024
#define NH 16
#define DHEAD 64
#define BATCH 4

typedef _Float16 half8 __attribute__((ext_vector_type(8)));
typedef __fp16 fp16x2 __attribute__((ext_vector_type(2)));
typedef float floatx4 __attribute__((ext_vector_type(4)));

#define EXP2SCALE 0.1803368801111244f   // (1/sqrt(64)) * log2(e), folded into Q projection

__device__ __forceinline__ unsigned short f2h(float f) {
    _Float16 h = (_Float16)f;
    return __builtin_bit_cast(unsigned short, h);
}

// single-instruction transcendentals (avoid ocml precise paths: no -ffast-math here)
__device__ __forceinline__ float fexp2(float x) {
    float r;
    asm("v_exp_f32 %0, %1" : "=v"(r) : "v"(x));
    return r;
}
__device__ __forceinline__ float frcp(float x) {
    float r;
    asm("v_rcp_f32 %0, %1" : "=v"(r) : "v"(x));
    return r;
}

// pack two floats -> 2x fp16 (RTZ) as uint bits
__device__ __forceinline__ unsigned int pk2(float a, float b) {
    fp16x2 p = __builtin_amdgcn_cvt_pkrtz(a, b);
    return __builtin_bit_cast(unsigned int, p);
}

// async global->LDS, 16B per lane; lds dest = wave-uniform base + lane*16
__device__ __forceinline__ void gload_lds16(const unsigned short* g, unsigned short* l) {
    __builtin_amdgcn_global_load_lds(
        (const __attribute__((address_space(1))) void*)g,
        (__attribute__((address_space(3))) void*)l,
        16, 0, 0);
}

// ---------------- conversion: fp32 -> fp16 bits ---------------------------------
__global__ __launch_bounds__(256) void convert_f2h_kernel(const float* __restrict__ in,
                                                          unsigned short* __restrict__ out,
                                                          int n4) {
    int i = blockIdx.x * 256 + threadIdx.x;
    if (i < n4) {
        float4 v = ((const float4*)in)[i];
        ushort4 o;
        o.x = f2h(v.x); o.y = f2h(v.y); o.z = f2h(v.z); o.w = f2h(v.w);
        ((ushort4*)out)[i] = o;
    }
}

// ---------------- 4 x (W [K][N] fp32 -> Wt [N][K] fp16) fused -------------------
__global__ __launch_bounds__(256) void transpose_w_kernel(const float* __restrict__ W0,
                                                          const float* __restrict__ W1,
                                                          const float* __restrict__ W2,
                                                          const float* __restrict__ W3,
                                                          unsigned short* __restrict__ T0,
                                                          unsigned short* __restrict__ T1,
                                                          unsigned short* __restrict__ T2,
                                                          unsigned short* __restrict__ T3) {
    const float* W = blockIdx.z == 0 ? W0 : blockIdx.z == 1 ? W1 : blockIdx.z == 2 ? W2 : W3;
    unsigned short* Wt = blockIdx.z == 0 ? T0 : blockIdx.z == 1 ? T1 : blockIdx.z == 2 ? T2 : T3;
    __shared__ float tile[32][33];
    int x = threadIdx.x;
    int y = threadIdx.y;
    int k0 = blockIdx.y * 32;
    int n0 = blockIdx.x * 32;
    for (int i = 0; i < 4; i++)
        tile[y + 8 * i][x] = W[(size_t)(k0 + y + 8 * i) * D_MODEL + n0 + x];
    __syncthreads();
    for (int i = 0; i < 4; i++)
        Wt[(size_t)(n0 + y + 8 * i) * D_MODEL + k0 + x] = f2h(tile[x][y + 8 * i]);
}

// ---------------- NT GEMM body, BK=64: C[M][N] = A[M][K] * Bt[N][K]^T ------------
// MODE 0: fp16 -> Q/K layout [b][h][s][dh], LDS-bounce coalesced stores (×osc)
// MODE 1: fp16 -> V^T layout [b][h][dh][s], LDS-bounce (transposed) stores
// MODE 2: fp32 -> [M][N] direct stores
template<int MODE>
__device__ __forceinline__ void gemm_body(const unsigned short* __restrict__ A,
                                          const unsigned short* __restrict__ Bt,
                                          void* __restrict__ Cout,
                                          int M, int N, int K,
                                          int bx, int by,
                                          unsigned short* smem, float osc) {
    unsigned short* As = smem;             // 128*64 halfs (16KB)
    unsigned short* Bs = smem + 8192;      // 128*64 halfs
    const int tid  = threadIdx.x;
    const int wave = tid >> 6;
    const int lane = tid & 63;
    const int quad = lane >> 4;
    const int l16  = lane & 15;
    const int wm = (wave >> 1) * 64;
    const int wn = (wave & 1) * 64;
    const int tm = by * 128;
    const int tn = bx * 128;

    // staging geometry: 1024 16B-chunks per 128x64 tile, 4 issues/thread/array
    int rowi[4], gci[4];
#pragma unroll
    for (int i = 0; i < 4; i++) {
        int ci = tid + i * 256;
        rowi[i] = ci >> 3;
        gci[i]  = (ci & 7) ^ (rowi[i] & 7);
    }

    floatx4 acc[4][4] = {};

    for (int k0 = 0; k0 < K; k0 += 64) {
        __syncthreads();
#pragma unroll
        for (int i = 0; i < 4; i++) {
            gload_lds16(A  + (size_t)(tm + rowi[i]) * K + k0 + gci[i] * 8, &As[i * 2048 + wave * 512]);
            gload_lds16(Bt + (size_t)(tn + rowi[i]) * K + k0 + gci[i] * 8, &Bs[i * 2048 + wave * 512]);
        }
        __syncthreads();

#pragma unroll
        for (int ks = 0; ks < 2; ks++) {
            half8 af[4], bf[4];
#pragma unroll
            for (int mi = 0; mi < 4; mi++) {
                int row = wm + mi * 16 + l16;
                af[mi] = *(const half8*)(&As[row * 64 + ((((ks << 2) | quad) ^ (row & 7)) << 3)]);
            }
#pragma unroll
            for (int ni = 0; ni < 4; ni++) {
                int row = wn + ni * 16 + l16;
                bf[ni] = *(const half8*)(&Bs[row * 64 + ((((ks << 2) | quad) ^ (row & 7)) << 3)]);
            }
#pragma unroll
            for (int mi = 0; mi < 4; mi++)
#pragma unroll
                for (int ni = 0; ni < 4; ni++)
                    acc[mi][ni] = __builtin_amdgcn_mfma_f32_16x16x32_f16(af[mi], bf[ni], acc[mi][ni], 0, 0, 0);
        }
    }

    if (MODE == 2) {
#pragma unroll
        for (int mi = 0; mi < 4; mi++)
#pragma unroll
            for (int ni = 0; ni < 4; ni++)
#pragma unroll
                for (int r = 0; r < 4; r++) {
                    int row = tm + wm + mi * 16 + quad * 4 + r;
                    int col = tn + wn + ni * 16 + l16;
                    ((float*)Cout)[(size_t)row * N + col] = acc[mi][ni][r];
                }
        return;
    }

    __syncthreads();   // all waves done reading As/Bs
    if (MODE == 0) {
#pragma unroll
        for (int mi = 0; mi < 4; mi++)
#pragma unroll
            for (int ni = 0; ni < 4; ni++) {
                int col = wn + ni * 16 + l16;
                int cc  = col >> 4;
                int cil = col & 15;
#pragma unroll
                for (int r = 0; r < 4; r++) {
                    int row = wm + mi * 16 + quad * 4 + r;
                    smem[row * 128 + ((cc ^ ((row >> 2) & 7)) << 4) + cil] = f2h(acc[mi][ni][r] * osc);
                }
            }
        __syncthreads();
        unsigned short* O = (unsigned short*)Cout;
#pragma unroll
        for (int j = 0; j < 8; j++) {
            int vid = tid + j * 256;
            int row = vid >> 4, vv = vid & 15;
            int cc = vv >> 1, hf = vv & 1;
            uint4 v = *(const uint4*)(&smem[row * 128 + ((cc ^ ((row >> 2) & 7)) << 4) + hf * 8]);
            int grow = tm + row;
            int b = grow >> 11, s = grow & 2047;
            int n = tn + vv * 8;
            int h = n >> 6, dh = n & 63;
            *(uint4*)(O + (((size_t)(b * NH + h) * S_LEN + s) * DHEAD + dh)) = v;
        }
    } else {
#pragma unroll
        for (int mi = 0; mi < 4; mi++)
#pragma unroll
            for (int ni = 0; ni < 4; ni++) {
                int col = wn + ni * 16 + l16;
                int sw  = (col >> 2) & 7;
#pragma unroll
                for (int r = 0; r < 4; r++) {
                    int row = wm + mi * 16 + quad * 4 + r;
                    smem[col * 128 + (((row >> 4) ^ sw) << 4) + (row & 15)] = f2h(acc[mi][ni][r]);
                }
            }
        __syncthreads();
        unsigned short* O = (unsigned short*)Cout;
        int b = tm >> 11;
        int sbase = tm & 2047;
#pragma unroll
        for (int j = 0; j < 8; j++) {
            int vid = tid + j * 256;
            int colr = vid >> 4, vv = vid & 15;
            int rc = vv >> 1, hf = vv & 1;
            uint4 v = *(const uint4*)(&smem[colr * 128 + ((rc ^ ((colr >> 2) & 7)) << 4) + hf * 8]);
            int n = tn + colr;
            int h = n >> 6, dh = n & 63;
            *(uint4*)(O + (((size_t)(b * NH + h) * DHEAD + dh) * S_LEN + sbase + vv * 8)) = v;
        }
    }
}

// fused QKV projection: z=0 Q (mode0, ×EXP2SCALE), z=1 K (mode0), z=2 V (mode1)
__global__ __launch_bounds__(256) void qkv_gemm_kernel(const unsigned short* __restrict__ A,
                                                       const unsigned short* __restrict__ Wq,
                                                       const unsigned short* __restrict__ Wk,
                                                       const unsigned short* __restrict__ Wv,
                                                       unsigned short* __restrict__ Qo,
                                                       unsigned short* __restrict__ Ko,
                                                       unsigned short* __restrict__ Vo) {
    __shared__ unsigned short smem[128 * 128];
    const int z = blockIdx.z;
    if (z == 2)
        gemm_body<1>(A, Wv, Vo, BATCH * S_LEN, D_MODEL, D_MODEL, blockIdx.x, blockIdx.y, smem, 1.f);
    else
        gemm_body<0>(A, z == 0 ? Wq : Wk, z == 0 ? Qo : Ko,
                     BATCH * S_LEN, D_MODEL, D_MODEL, blockIdx.x, blockIdx.y, smem,
                     z == 0 ? EXP2SCALE : 1.f);
}

__global__ __launch_bounds__(256) void out_gemm_kernel(const unsigned short* __restrict__ A,
                                                       const unsigned short* __restrict__ Bt,
                                                       float* __restrict__ C) {
    __shared__ unsigned short smem[128 * 128];
    gemm_body<2>(A, Bt, C, BATCH * S_LEN, D_MODEL, D_MODEL, blockIdx.x, blockIdx.y, smem, 1.f);
}

// ---------------- Flash attention v5 (causal), dual-tile + K/V double-buffer ----
// Q (pre-scaled), K: [b][h][s][dh] fp16 ; Vt: [b][h][dh][s] fp16 ; ctx fp16.
// 512 threads / 8 waves. Waves 0-3 own q-tile ta=bx, waves 4-7 own tb=15-bx.
// One barrier per round: prefetch kt+1 into alternate buffer, compute kt.
// Grid (8, NH, B) = 512 blocks = 2/CU (LDS 69.6KB).
__global__ __launch_bounds__(512, 4) void attn_kernel(const unsigned short* __restrict__ Q,
                                                      const unsigned short* __restrict__ K,
                                                      const unsigned short* __restrict__ Vt,
                                                      unsigned short* __restrict__ ctx) {
    __shared__ unsigned short smem[34816];   // K0|K1|V0|V1 (4x4096) | Ps 8*2304
    unsigned short* Ps = smem + 16384;
    const int tid  = threadIdx.x;
    const int wave = tid >> 6;
    const int wg   = wave >> 2;        // 0 = tile A, 1 = tile B
    const int wv   = wave & 3;
    const int lane = tid & 63;
    const int quad = lane >> 4;
    const int l16  = lane & 15;
    const int bx = blockIdx.x;         // 0..7
    const int h  = blockIdx.y;
    const int b  = blockIdx.z;
    const size_t head = (size_t)(b * NH + h) * (S_LEN * DHEAD);

    const int ta = bx, tb = 15 - bx;
    const int tw = wg ? tb : ta;
    const int rounds = 2 * tb + 2;
    const int dk  = 2 * tw + (wv >> 1);
    const int qg0 = tw * 128 + wv * 32 + l16;

    // Q B-fragments (global layout == frag layout), Q pre-scaled by EXP2SCALE
    half8 qf[2][2];
#pragma unroll
    for (int s = 0; s < 2; s++)
#pragma unroll
        for (int ks = 0; ks < 2; ks++)
            qf[s][ks] = *(const half8*)(Q + head + (size_t)(qg0 + s * 16) * DHEAD + ks * 32 + quad * 8);

    // staging: 512 threads x 16B = one 64x64 tile per array per round
    const int r0 = tid >> 3;
    const int g0 = (tid & 7) ^ (r0 & 7);
    const unsigned short* pK = K  + head + (size_t)r0 * DHEAD + g0 * 8;
    const unsigned short* pV = Vt + head + (size_t)r0 * S_LEN + g0 * 8;
    const int sdst = wave * 512;       // wave-uniform dest within buffer

    // hoisted LDS read bases (half indices)
    const int akb0 = l16 * 64 + ((quad    ) ^ (l16 & 7)) * 8;   // ks=0
    const int akb1 = l16 * 64 + ((4 | quad) ^ (l16 & 7)) * 8;   // ks=1
    const int psr  = wave * 2304 + l16 * 72;                    // Ps set0 row base

    floatx4 acc0[4] = {}, acc1[4] = {};
    float m0 = -3.0e38f, l0 = 0.f, m1 = -3.0e38f, l1 = 0.f;

    // prologue: stage kt=0 into buffer 0
    gload_lds16(pK, smem + sdst);
    gload_lds16(pV, smem + 8192 + sdst);
    pK += 64 * DHEAD; pV += 64;

    for (int c = 0; c < rounds; c++) {
        __syncthreads();   // buf[c&1] loads complete; buf[(c+1)&1] readers done
        const int cur = c & 1;
        if (c + 1 < rounds) {
            gload_lds16(pK, smem + (cur ^ 1) * 4096 + sdst);
            gload_lds16(pV, smem + 8192 + (cur ^ 1) * 4096 + sdst);
            pK += 64 * DHEAD; pV += 64;
        }
        if (c > dk) continue;

        const unsigned short* Ksb = smem + cur * 4096;
        const unsigned short* Vsb = smem + 8192 + cur * 4096;

        // S^T = K Q^T ; sc C-layout: col=q=l16, row=kk=mk*16+quad*4+r
        floatx4 sc0[4] = {}, sc1[4] = {};
#pragma unroll
        for (int ks = 0; ks < 2; ks++) {
            const int ab = ks ? akb1 : akb0;
#pragma unroll
            for (int mk = 0; mk < 4; mk++) {
                half8 ak = *(const half8*)(&Ksb[mk * 1024 + ab]);
                sc0[mk] = __builtin_amdgcn_mfma_f32_16x16x32_f16(ak, qf[0][ks], sc0[mk], 0, 0, 0);
                sc1[mk] = __builtin_amdgcn_mfma_f32_16x16x32_f16(ak, qf[1][ks], sc1[mk], 0, 0, 0);
            }
        }

        const bool diag = (c == dk);

#define SOFTMAX_SET(sc, m_s, l_s, acc, qg, setofs)                                \
        {                                                                         \
            if (diag) {                                                           \
                int rel = (qg) - c * 64 - quad * 4;                               \
                _Pragma("unroll")                                                 \
                for (int mk = 0; mk < 4; mk++)                                    \
                    _Pragma("unroll")                                             \
                    for (int r = 0; r < 4; r++)                                   \
                        if (mk * 16 + r > rel) sc[mk][r] = -3.0e38f;              \
            }                                                                     \
            float mx = sc[0][0];                                                  \
            _Pragma("unroll")                                                     \
            for (int mk = 0; mk < 4; mk++)                                        \
                _Pragma("unroll")                                                 \
                for (int r = 0; r < 4; r++)                                       \
                    if (mk || r) mx = fmaxf(mx, sc[mk][r]);                       \
            mx = fmaxf(mx, __shfl_xor(mx, 16, 64));                               \
            mx = fmaxf(mx, __shfl_xor(mx, 32, 64));                               \
            float mold = m_s;                                                     \
            float mn = fmaxf(mold, mx);                                           \
            float al = fexp2(mold - mn);                                          \
            m_s = mn;                                                             \
            float rs = 0.f;                                                       \
            _Pragma("unroll")                                                     \
            for (int mk = 0; mk < 4; mk++)                                        \
                _Pragma("unroll")                                                 \
                for (int r = 0; r < 4; r++) {                                     \
                    float e = fexp2(sc[mk][r] - mn);                               \
                    sc[mk][r] = e;                                                 \
                    rs += e;                                                       \
                }                                                                 \
            rs += __shfl_xor(rs, 16, 64);                                         \
            rs += __shfl_xor(rs, 32, 64);                                         \
            l_s = l_s * al + rs;                                                  \
            if (__any(mold != mn)) {                                              \
                _Pragma("unroll")                                                 \
                for (int db = 0; db < 4; db++)                                    \
                    _Pragma("unroll")                                             \
                    for (int r = 0; r < 4; r++) acc[db][r] *= al;                 \
            }                                                                     \
            _Pragma("unroll")                                                     \
            for (int mk = 0; mk < 4; mk++) {                                      \
                uint2 u;                                                          \
                u.x = pk2(sc[mk][0], sc[mk][1]);                                  \
                u.y = pk2(sc[mk][2], sc[mk][3]);                                  \
                *(uint2*)(&Ps[psr + (setofs) + mk * 16 + quad * 4]) = u;          \
            }                                                                     \
        }

        SOFTMAX_SET(sc0, m0, l0, acc0, qg0,      0)
        SOFTMAX_SET(sc1, m1, l1, acc1, qg0 + 16, 1152)
#undef SOFTMAX_SET

        // O^T += V^T P^T : A = Vs rows (dh), B = own-wave Ps rows (q)
#pragma unroll
        for (int ks = 0; ks < 2; ks++) {
            const int ab = ks ? akb1 : akb0;
            half8 bp0 = *(const half8*)(&Ps[psr        + ks * 32 + quad * 8]);
            half8 bp1 = *(const half8*)(&Ps[psr + 1152 + ks * 32 + quad * 8]);
#pragma unroll
            for (int db = 0; db < 4; db++) {
                half8 av = *(const half8*)(&Vsb[db * 1024 + ab]);
                acc0[db] = __builtin_amdgcn_mfma_f32_16x16x32_f16(av, bp0, acc0[db], 0, 0, 0);
                acc1[db] = __builtin_amdgcn_mfma_f32_16x16x32_f16(av, bp1, acc1[db], 0, 0, 0);
            }
        }
    }

    // ---- epilogue: O^T -> LDS bounce (256 rows x 64 halfs) -> coalesced stores --
    __syncthreads();   // everyone done with K/V/Ps
#pragma unroll
    for (int s = 0; s < 2; s++) {
        float inv = frcp(s ? l1 : l0);
        int qrow = wg * 128 + wv * 32 + s * 16 + l16;   // 0..255 local
        floatx4* ac = s ? acc1 : acc0;
#pragma unroll
        for (int db = 0; db < 4; db++) {
            uint2 u;
            u.x = pk2(ac[db][0] * inv, ac[db][1] * inv);
            u.y = pk2(ac[db][2] * inv, ac[db][3] * inv);
            int chunk = db * 2 + (quad >> 1);
            int sw = chunk ^ (qrow & 7);
            *(uint2*)(&smem[qrow * 64 + sw * 8 + (quad & 1) * 4]) = u;
        }
    }
    __syncthreads();
#pragma unroll
    for (int j = 0; j < 4; j++) {
        int vid = j * 512 + tid;              // 0..2047
        int ql = vid >> 3, slot = vid & 7;    // ql: 0..255 local row
        uint4 v = *(const uint4*)(&smem[ql * 64 + slot * 8]);
        int dhc = slot ^ (ql & 7);
        int q = (ql < 128 ? ta * 128 : tb * 128 - 128) + ql;
        *(uint4*)(ctx + ((size_t)b * S_LEN + q) * D_MODEL + h * DHEAD + dhc * 8) = v;
    }
}

extern "C" void kernel_launch(void* const* d_in, const int* in_sizes, int n_in,
                              void* d_out, int out_size, void* d_ws, size_t ws_size,
                              hipStream_t stream) {
    const float* x  = (const float*)d_in[0];
    const float* Wq = (const float*)d_in[1];
    const float* Wk = (const float*)d_in[2];
    const float* Wv = (const float*)d_in[3];
    const float* Wo = (const float*)d_in[4];

    char* ws = (char*)d_ws;
    unsigned short* Xh   = (unsigned short*)(ws + 0);            // 16 MB
    unsigned short* Wqt  = (unsigned short*)(ws + 16777216);     // 2 MB
    unsigned short* Wkt  = (unsigned short*)(ws + 18874368);     // 2 MB
    unsigned short* Wvt  = (unsigned short*)(ws + 20971520);     // 2 MB
    unsigned short* Wot  = (unsigned short*)(ws + 23068672);     // 2 MB
    unsigned short* Qh   = (unsigned short*)(ws + 25165824);     // 16 MB
    unsigned short* Kh   = (unsigned short*)(ws + 41943040);     // 16 MB
    unsigned short* Vth  = (unsigned short*)(ws + 58720256);     // 16 MB
    unsigned short* ctxh = (unsigned short*)(ws + 75497472);     // 16 MB

    const int M = BATCH * S_LEN;   // 8192

    convert_f2h_kernel<<<(M * D_MODEL / 4 + 255) / 256, 256, 0, stream>>>(x, Xh, M * D_MODEL / 4);
    transpose_w_kernel<<<dim3(32, 32, 4), dim3(32, 8), 0, stream>>>(Wq, Wk, Wv, Wo, Wqt, Wkt, Wvt, Wot);

    qkv_gemm_kernel<<<dim3(8, 64, 3), 256, 0, stream>>>(Xh, Wqt, Wkt, Wvt, Qh, Kh, Vth);

    attn_kernel<<<dim3(8, NH, BATCH), 512, 0, stream>>>(Qh, Kh, Vth, ctxh);

    out_gemm_kernel<<<dim3(8, 64), 256, 0, stream>>>(ctxh, Wot, (float*)d_out);
}